// Round 2
// baseline (131.860 us; speedup 1.0000x reference)
//
#include <hip/hip_runtime.h>

#define IS 256
#define NEARV 0.1f
#define FARV 100.0f
#define NTX 16                    // 16x16 tiles of 16x16 px
#define NTILES 256
#define SEGSZ 256                 // faces per segment == threads per prep block
#define NSEGMAX 20                // ceil(5120 / SEGSZ); nf=5000 -> nseg=20
#define CAP (SEGSZ * NSEGMAX)     // per-tile list region (segmented, 5120)
#define CHK 32                    // entries per raster chunk
#define RBLOCKS 2048
#define RWAVES (RBLOCKS * 4)
#define NSLOTS (NTILES * 256)     // 256 tiles x (32 seg-slots x 8 chunk-slots)

// ---------------- kernel 1: init + prep + segmented bin ----------------
// 256 blocks x 256 threads. Every thread inits one zb pixel (grid == IS*IS
// exactly; d_out holds raw float bits, atomicMin'd; positive floats compare
// as uints). Blocks 0..nseg-1 additionally transform+cull one face per
// thread (arithmetic expression-identical to all verified rounds) and bin
// into SEGMENTED per-tile lists: segment b owns slots [b*SEGSZ, b*SEGSZ+SEGSZ)
// of every tile's CAP region, so binning needs NO global atomics, NO count
// zeroing, NO ticket/fences. Per-(tile,seg) counts go to cnt2 (plain stores;
// the kernel boundary provides cross-XCD visibility for kraster).
__launch_bounds__(256)
__global__ void kprep(const float* __restrict__ verts, const int* __restrict__ faces,
                      float4* __restrict__ fd, int* __restrict__ cnt2,
                      unsigned short* __restrict__ list, unsigned int* __restrict__ zb,
                      int nf, int nseg) {
    __shared__ int scnt[NTILES];
    const int tid = threadIdx.x;
    const int bid = blockIdx.x;
    zb[bid * 256 + tid] = 0x42C80000u;  // __float_as_uint(100.0f)
    if (bid >= nseg) return;            // uniform per block: no divergent barrier

    scnt[tid] = 0;                      // NTILES == blockDim == 256
    __syncthreads();

    const int f = bid * 256 + tid;
    int kx0 = 0, kx1 = -1, ky0 = 0, ky1 = -1;   // empty range for dead faces
    float bxmin = 0.f, bymin = 0.f, bxmax = -1.f, bymax = -1.f;
    if (f < nf) {
        int i0 = faces[f * 3 + 0];
        int i1 = faces[f * 3 + 1];
        int i2 = faces[f * 3 + 2];
        // transform (v - eye; R == I exactly in fp32 for this camera)
        float z0 = verts[i0 * 3 + 2] + 2.7320508075688772f;
        float z1 = verts[i1 * 3 + 2] + 2.7320508075688772f;
        float z2 = verts[i2 * 3 + 2] + 2.7320508075688772f;
        bool front = (z0 > NEARV) && (z1 > NEARV) && (z2 > NEARV);
        float zs0 = (fabsf(z0) < 1e-5f) ? 1e-5f : z0;
        float zs1 = (fabsf(z1) < 1e-5f) ? 1e-5f : z1;
        float zs2 = (fabsf(z2) < 1e-5f) ? 1e-5f : z2;
        float d0 = zs0 * 0.57735026918962576f;  // zs * tan(30 deg)
        float d1 = zs1 * 0.57735026918962576f;
        float d2 = zs2 * 0.57735026918962576f;
        float x0 = verts[i0 * 3 + 0] / d0;
        float y0 = verts[i0 * 3 + 1] / d0;
        float x1 = verts[i1 * 3 + 0] / d1;
        float y1 = verts[i1 * 3 + 1] / d1;
        float x2 = verts[i2 * 3 + 0] / d2;
        float y2 = verts[i2 * 3 + 1] / d2;
        float area = (x1 - x0) * (y2 - y0) - (x2 - x0) * (y1 - y0);
        if (front && (fabsf(area) > 1e-8f)) {
            bxmin = fminf(x0, fminf(x1, x2));
            bxmax = fmaxf(x0, fmaxf(x1, x2));
            bymin = fminf(y0, fminf(y1, y2));
            bymax = fmaxf(y0, fmaxf(y1, y2));
            float ia = 1.0f / area;  // |area| > 1e-8 so area_s == area
            float iz0 = 1.0f / fmaxf(z0, 1e-4f);
            float iz1 = 1.0f / fmaxf(z1, 1e-4f);
            float iz2 = 1.0f / fmaxf(z2, 1e-4f);
            float4* o = fd + (size_t)f * 4;
            o[0] = make_float4(x0, y0, x1, y1);
            o[1] = make_float4(x2, y2, ia, iz0);
            o[2] = make_float4(iz1, iz2, 0.0f, 0.0f);
            // conservative k-range (+/-1), exact predicate re-tested below
            float tminx = fminf(fmaxf((bxmin * 256.0f + 225.0f) * (1.0f / 32.0f), -2.0f), 17.0f);
            float tmaxx = fminf(fmaxf((bxmax * 256.0f + 255.0f) * (1.0f / 32.0f), -2.0f), 17.0f);
            float tminy = fminf(fmaxf((bymin * 256.0f + 225.0f) * (1.0f / 32.0f), -2.0f), 17.0f);
            float tmaxy = fminf(fmaxf((bymax * 256.0f + 255.0f) * (1.0f / 32.0f), -2.0f), 17.0f);
            kx0 = max(0, (int)ceilf(tminx) - 1);
            kx1 = min(NTX - 1, (int)floorf(tmaxx) + 1);
            ky0 = max(0, (int)ceilf(tminy) - 1);
            ky1 = min(NTX - 1, (int)floorf(tmaxy) + 1);
        }
    }
    // pass A: count (exact dyadic tile-overlap predicate -> bit-identical sets)
    for (int ky = ky0; ky <= ky1; ++ky) {
        float py_lo = (float)(32 * ky - 255) * (1.0f / 256.0f);
        float py_hi = (float)(32 * ky - 225) * (1.0f / 256.0f);
        if (!(bymin <= py_hi && bymax >= py_lo)) continue;
        for (int kx = kx0; kx <= kx1; ++kx) {
            float px_lo = (float)(32 * kx - 255) * (1.0f / 256.0f);
            float px_hi = (float)(32 * kx - 225) * (1.0f / 256.0f);
            if (bxmin <= px_hi && bxmax >= px_lo) atomicAdd(&scnt[ky * NTX + kx], 1);
        }
    }
    __syncthreads();
    cnt2[tid * nseg + bid] = scnt[tid];  // tile == tid; unconditional (zeros too)
    scnt[tid] = 0;                       // reuse as per-segment cursor
    __syncthreads();
    // pass B: scatter into this block's own segment (no inter-block contention;
    // order within a tile list is irrelevant: min is commutative)
    for (int ky = ky0; ky <= ky1; ++ky) {
        float py_lo = (float)(32 * ky - 255) * (1.0f / 256.0f);
        float py_hi = (float)(32 * ky - 225) * (1.0f / 256.0f);
        if (!(bymin <= py_hi && bymax >= py_lo)) continue;
        for (int kx = kx0; kx <= kx1; ++kx) {
            float px_lo = (float)(32 * kx - 255) * (1.0f / 256.0f);
            float px_hi = (float)(32 * kx - 225) * (1.0f / 256.0f);
            if (bxmin <= px_hi && bxmax >= px_lo) {
                int t = ky * NTX + kx;
                int slot = atomicAdd(&scnt[t], 1);               // < SEGSZ by construction
                list[(size_t)t * CAP + bid * SEGSZ + slot] = (unsigned short)f;
            }
        }
    }
}

// ---------------- kernel 2: raster ----------------
// Static work enumeration: 65536 potential (tile, seg, chunk) slots, 8 uniform
// iterations per wave -- NO items array, NO nitems load, NO serial item build.
// slot is XOR-scrambled by tile (bijective within each tile) to decorrelate a
// wave's 8 slots in (seg,chunk) space for load balance. Empty slots cost a few
// SALU + one scalar cnt2 load (sL1-hot, 20 KB). Per active chunk: <=32
// pre-matched entries, 16x16 px tile, 4 px/lane. Wave-uniform values go
// through readfirstlane so per-entry face reads are scalar loads; list read as
// uint pairs. zb pre-read per pixel; atomicMin only when it would win (zb is
// monotone-decreasing -> stale read conservatively safe). Pixel math
// expression-identical to verified rounds; min3 predicate is an exact
// reformulation of the three sign tests.
__launch_bounds__(256)
__global__ void kraster(const float4* __restrict__ fd, const unsigned int* __restrict__ list32,
                        const int* __restrict__ cnt2, unsigned int* __restrict__ zb,
                        int nseg) {
    const int wslot = __builtin_amdgcn_readfirstlane(threadIdx.x >> 6);
    const int wid = blockIdx.x * 4 + wslot;
    const int lane = threadIdx.x & 63;
    const int cx = lane & 15;
    const int ry = lane >> 4;

    for (int w = wid; w < NSLOTS; w += RWAVES) {
        const int tile = w >> 8;
        const int slot = (w & 255) ^ tile;   // tile<256: bijective scramble
        const int seg = slot >> 3;
        if (seg >= nseg) continue;
        const int c = cnt2[tile * nseg + seg];
        const int k = slot & 7;
        const int n0 = c - k * CHK;
        if (n0 <= 0) continue;
        const int n = min(CHK, n0);

        const int bx = tile & 15;
        const int by = tile >> 4;
        const int j = bx * 16 + cx;
        const float px = ((float)(2 * j + 1) - 256.0f) * (1.0f / 256.0f);
        float py[4];
        int row[4];
        unsigned int zcur[4];
#pragma unroll
        for (int r = 0; r < 4; ++r) {
            row[r] = by * 16 + ry + 4 * r;
            py[r] = ((float)(2 * row[r] + 1) - 256.0f) * (1.0f / 256.0f);
            zcur[r] = zb[row[r] * IS + j];
        }
        // list base in uints: all terms even -> aligned
        const unsigned int* lp32 = list32 + ((size_t)tile * CAP + seg * SEGSZ + k * CHK) / 2;

        float mx[4] = {0.0f, 0.0f, 0.0f, 0.0f};
        unsigned int pr = 0;

#pragma unroll 2
        for (int e = 0; e < n; ++e) {
            if ((e & 1) == 0)
                pr = (unsigned int)__builtin_amdgcn_readfirstlane((int)lp32[e >> 1]);
            const int fidx = (e & 1) ? (int)(pr >> 16) : (int)(pr & 0xffffu);
            const float4* p = fd + (size_t)fidx * 4;
            float4 a0 = p[0];
            float4 a1 = p[1];
            float4 a2 = p[2];
            float dx0 = a0.x - px, dx1 = a0.z - px, dx2 = a1.x - px;
#pragma unroll
            for (int r = 0; r < 4; ++r) {
                float dy0 = a0.y - py[r], dy1 = a0.w - py[r], dy2 = a1.y - py[r];
                float e0 = dx1 * dy2 - dx2 * dy1;
                float e1 = dx2 * dy0 - dx0 * dy2;
                float w0 = e0 * a1.z;
                float w1 = e1 * a1.z;
                float w2 = 1.0f - w0 - w1;
                float invz = w0 * a1.w + w1 * a2.x + w2 * a2.y;
                float invzc = fmaxf(invz, 1e-6f);
                // all(w>=0) <=> min3(w0,w1,w2)>=0 (exact; mult by positive ia
                // preserves sign). valid NEAR<zp<FAR <=> 0.01 < invzc < 10.
                float wmin = fminf(fminf(w0, w1), w2);
                bool ok = (wmin >= 0.0f) && (invzc < 10.0f) && (invzc > 0.01f);
                if (ok) mx[r] = fmaxf(mx[r], invzc);
            }
        }
#pragma unroll
        for (int r = 0; r < 4; ++r) {
            if (mx[r] > 0.0f) {
                float zp = 1.0f / mx[r];  // correctly-rounded 1/x monotone => min-exact
                unsigned int zbits = __float_as_uint(zp);
                if (zbits < zcur[r]) atomicMin(&zb[row[r] * IS + j], zbits);
            }
        }
    }
}

extern "C" void kernel_launch(void* const* d_in, const int* in_sizes, int n_in,
                              void* d_out, int out_size, void* d_ws, size_t ws_size,
                              hipStream_t stream) {
    const float* verts = (const float*)d_in[0];
    const int* faces = (const int*)d_in[1];
    unsigned int* zb = (unsigned int*)d_out;  // float bits, min'd in place

    const int nf = in_sizes[1] / 3;           // 5000 (<= CAP, < 65536: ushort ok)
    const int nseg = (nf + SEGSZ - 1) / SEGSZ;  // 20 (<= NSEGMAX)

    char* ws = (char*)d_ws;
    size_t off = 0;
    float4* fd = (float4*)(ws + off);     off += (size_t)nf * 64;            // 320 KB
    off = (off + 255) & ~(size_t)255;
    int* cnt2 = (int*)(ws + off);         off += (size_t)NTILES * NSEGMAX * 4;  // 20 KB
    off = (off + 255) & ~(size_t)255;
    unsigned short* list = (unsigned short*)(ws + off);  // 256*5120*2 = 2.62 MB

    kprep<<<256, 256, 0, stream>>>(verts, faces, fd, cnt2, list, zb, nf, nseg);
    kraster<<<RBLOCKS, 256, 0, stream>>>(fd, (const unsigned int*)list, cnt2, zb, nseg);
}

// Round 3
// 107.756 us; speedup vs baseline: 1.2237x; 1.2237x over previous
//
#include <hip/hip_runtime.h>

#define IS 256
#define NEARV 0.1f
#define FARV 100.0f
#define NTX 16                    // 16x16 tiles of 16x16 px
#define NTILES 256
#define CAP 5120                  // per-tile list capacity >= nf -> overflow impossible
#define CHK 32                    // entries per raster work item
#define CPT ((CAP + CHK - 1) / CHK)   // max chunks per tile = 160
#define RBLOCKS 2048
#define RWAVES (RBLOCKS * 4)
#define MAXITEMS (NTILES * CPT)

// ---------------- kernel 1: init ----------------
// zb (d_out; raw float bits, atomicMin'd; positive floats compare as uints)
// init to 100.0f = FAR; zero tile counts and the completion ticket.
__global__ void kinit(unsigned int* __restrict__ zb, int* __restrict__ count,
                      int* __restrict__ misc) {
    int i = blockIdx.x * 256 + threadIdx.x;
    zb[i] = 0x42C80000u;  // __float_as_uint(100.0f); grid == IS*IS exactly
    if (i < NTILES) count[i] = 0;
    if (i == NTILES) misc[0] = 0;  // ticket
}

// ---------------- kernel 2: fused prep + bin + items ----------------
// (verbatim round-1 structure: benched 110.9 with absmax 0.0)
// Per thread: gather+transform+cull its face in registers (arithmetic
// expression-identical to all verified rounds), write the 48B raster record,
// bin via two-level LDS counting (one global atomicAdd per (block,tile)
// nonzero -> contiguous per-tile lists). The LAST block (global ticket,
// release/acquire threadfences) builds the compacted item list with a
// Hillis-Steele scan. item = (tile << 16) | (n << 8) | chunk, n <= 32.
__launch_bounds__(256)
__global__ void kbinprep(const float* __restrict__ verts, const int* __restrict__ faces,
                         float4* __restrict__ fd, int* __restrict__ count,
                         unsigned short* __restrict__ list, int* __restrict__ misc,
                         int* __restrict__ items, int nf) {
    __shared__ int scnt[NTILES];
    __shared__ int sbase[NTILES];
    __shared__ int slast;
    const int tid = threadIdx.x;
    for (int t = tid; t < NTILES; t += 256) scnt[t] = 0;
    __syncthreads();

    const int f = blockIdx.x * 256 + tid;
    int kx0 = 0, kx1 = -1, ky0 = 0, ky1 = -1;     // empty range for dead faces
    float bxmin = 0.f, bymin = 0.f, bxmax = -1.f, bymax = -1.f;
    if (f < nf) {
        int i0 = faces[f * 3 + 0];
        int i1 = faces[f * 3 + 1];
        int i2 = faces[f * 3 + 2];
        // transform (v - eye; R == I exactly in fp32 for this camera)
        float z0 = verts[i0 * 3 + 2] + 2.7320508075688772f;
        float z1 = verts[i1 * 3 + 2] + 2.7320508075688772f;
        float z2 = verts[i2 * 3 + 2] + 2.7320508075688772f;
        bool front = (z0 > NEARV) && (z1 > NEARV) && (z2 > NEARV);
        float zs0 = (fabsf(z0) < 1e-5f) ? 1e-5f : z0;
        float zs1 = (fabsf(z1) < 1e-5f) ? 1e-5f : z1;
        float zs2 = (fabsf(z2) < 1e-5f) ? 1e-5f : z2;
        float d0 = zs0 * 0.57735026918962576f;  // zs * tan(30 deg)
        float d1 = zs1 * 0.57735026918962576f;
        float d2 = zs2 * 0.57735026918962576f;
        float x0 = verts[i0 * 3 + 0] / d0;
        float y0 = verts[i0 * 3 + 1] / d0;
        float x1 = verts[i1 * 3 + 0] / d1;
        float y1 = verts[i1 * 3 + 1] / d1;
        float x2 = verts[i2 * 3 + 0] / d2;
        float y2 = verts[i2 * 3 + 1] / d2;
        float area = (x1 - x0) * (y2 - y0) - (x2 - x0) * (y1 - y0);
        if (front && (fabsf(area) > 1e-8f)) {
            bxmin = fminf(x0, fminf(x1, x2));
            bxmax = fmaxf(x0, fmaxf(x1, x2));
            bymin = fminf(y0, fminf(y1, y2));
            bymax = fmaxf(y0, fmaxf(y1, y2));
            float ia = 1.0f / area;  // |area| > 1e-8 so area_s == area
            float iz0 = 1.0f / fmaxf(z0, 1e-4f);
            float iz1 = 1.0f / fmaxf(z1, 1e-4f);
            float iz2 = 1.0f / fmaxf(z2, 1e-4f);
            float4* o = fd + (size_t)f * 4;
            o[0] = make_float4(x0, y0, x1, y1);
            o[1] = make_float4(x2, y2, ia, iz0);
            o[2] = make_float4(iz1, iz2, 0.0f, 0.0f);
            // conservative k-range (+/-1), exact predicate re-tested below
            float tminx = fminf(fmaxf((bxmin * 256.0f + 225.0f) * (1.0f / 32.0f), -2.0f), 17.0f);
            float tmaxx = fminf(fmaxf((bxmax * 256.0f + 255.0f) * (1.0f / 32.0f), -2.0f), 17.0f);
            float tminy = fminf(fmaxf((bymin * 256.0f + 225.0f) * (1.0f / 32.0f), -2.0f), 17.0f);
            float tmaxy = fminf(fmaxf((bymax * 256.0f + 255.0f) * (1.0f / 32.0f), -2.0f), 17.0f);
            kx0 = max(0, (int)ceilf(tminx) - 1);
            kx1 = min(NTX - 1, (int)floorf(tmaxx) + 1);
            ky0 = max(0, (int)ceilf(tminy) - 1);
            ky1 = min(NTX - 1, (int)floorf(tmaxy) + 1);
        }
    }
    // pass A: count (exact dyadic tile-overlap predicate -> bit-identical sets)
    for (int ky = ky0; ky <= ky1; ++ky) {
        float py_lo = (float)(32 * ky - 255) * (1.0f / 256.0f);
        float py_hi = (float)(32 * ky - 225) * (1.0f / 256.0f);
        if (!(bymin <= py_hi && bymax >= py_lo)) continue;
        for (int kx = kx0; kx <= kx1; ++kx) {
            float px_lo = (float)(32 * kx - 255) * (1.0f / 256.0f);
            float px_hi = (float)(32 * kx - 225) * (1.0f / 256.0f);
            if (bxmin <= px_hi && bxmax >= px_lo) atomicAdd(&scnt[ky * NTX + kx], 1);
        }
    }
    __syncthreads();
    for (int t = tid; t < NTILES; t += 256) {
        int c = scnt[t];
        sbase[t] = (c > 0) ? atomicAdd(&count[t], c) : 0;
        scnt[t] = 0;  // reuse as per-block cursor
    }
    __syncthreads();
    // pass B: scatter (order within a tile list irrelevant: min is commutative)
    for (int ky = ky0; ky <= ky1; ++ky) {
        float py_lo = (float)(32 * ky - 255) * (1.0f / 256.0f);
        float py_hi = (float)(32 * ky - 225) * (1.0f / 256.0f);
        if (!(bymin <= py_hi && bymax >= py_lo)) continue;
        for (int kx = kx0; kx <= kx1; ++kx) {
            float px_lo = (float)(32 * kx - 255) * (1.0f / 256.0f);
            float px_hi = (float)(32 * kx - 225) * (1.0f / 256.0f);
            if (bxmin <= px_hi && bxmax >= px_lo) {
                int t = ky * NTX + kx;
                int slot = sbase[t] + atomicAdd(&scnt[t], 1);
                list[(size_t)t * CAP + slot] = (unsigned short)f;
            }
        }
    }
    // ---- last-block epilogue: build item list (needs only final count[]) ----
    __syncthreads();
    __threadfence();  // release: our count[] atomicAdds before the ticket RMW
    if (tid == 0) slast = (atomicAdd(&misc[0], 1) == (int)gridDim.x - 1) ? 1 : 0;
    __syncthreads();
    if (!slast) return;
    __threadfence();  // acquire: see every block's count[] updates
    int c = __hip_atomic_load(&count[tid], __ATOMIC_RELAXED, __HIP_MEMORY_SCOPE_AGENT);
    int nch = (c + CHK - 1) / CHK;
    scnt[tid] = nch;
    __syncthreads();
    // Hillis-Steele inclusive scan over 256 tiles
    for (int d = 1; d < NTILES; d <<= 1) {
        int v = (tid >= d) ? scnt[tid - d] : 0;
        __syncthreads();
        scnt[tid] += v;
        __syncthreads();
    }
    int off = scnt[tid] - nch;
    if (tid == NTILES - 1) misc[64] = scnt[tid];  // nitems
    for (int k = 0; k < nch; ++k) {
        int n = min(CHK, c - k * CHK);
        items[off + k] = (tid << 16) | (n << 8) | k;
    }
}

// ---------------- kernel 3: raster ----------------
// One wave per item (ni < RWAVES -> at most ONE chunk per wave, perfect static
// balance). NEW vs round 1/2: batch-staged inner loop. Lanes 0..n-1 each load
// one entry's index (coalesced ushort) + its 48B face record (3x dwordx4, all
// concurrently in flight -- ONE vmcnt batch per chunk instead of 32 serial
// load->readfirstlane->s_load chains), stage to wave-private LDS, then the
// entry loop reads via same-address ds_read_b128 (LDS broadcast, conflict-
// free, compiler-pipelined). Write->read ordering is wave-internal:
// s_waitcnt lgkmcnt(0), no barrier (waves have different trip counts).
// Pixel math expression-identical to all verified rounds; min3 predicate is
// an exact reformulation of the three sign tests. zb pre-read per pixel;
// atomicMin only when it would win (zb monotone-decreasing -> stale read
// conservatively safe).
__launch_bounds__(256)
__global__ void kraster(const float4* __restrict__ fd, const unsigned short* __restrict__ list,
                        const int* __restrict__ items, const int* __restrict__ misc,
                        unsigned int* __restrict__ zb) {
    __shared__ float4 sdata[4][CHK * 3];   // 6 KB: [wave][entry*3 + part]
    const int wslot = __builtin_amdgcn_readfirstlane(threadIdx.x >> 6);
    const int wid = blockIdx.x * 4 + wslot;
    const int lane = threadIdx.x & 63;
    const int cx = lane & 15;
    const int ry = lane >> 4;
    const int ni = __builtin_amdgcn_readfirstlane(misc[64]);
    float4* sd = &sdata[wslot][0];

    for (int it = wid; it < ni; it += RWAVES) {
        const int pk = __builtin_amdgcn_readfirstlane(items[it]);
        const int tile = pk >> 16;
        const int n = (pk >> 8) & 0xff;
        const int chunk = pk & 0xff;
        const int bx = tile & 15;
        const int by = tile >> 4;
        const int j = bx * 16 + cx;
        const float px = ((float)(2 * j + 1) - 256.0f) * (1.0f / 256.0f);
        float py[4];
        int row[4];
        unsigned int zcur[4];
#pragma unroll
        for (int r = 0; r < 4; ++r) {
            row[r] = by * 16 + ry + 4 * r;
            py[r] = ((float)(2 * row[r] + 1) - 256.0f) * (1.0f / 256.0f);
            zcur[r] = zb[row[r] * IS + j];
        }
        // ---- stage this chunk's face records into wave-private LDS ----
        const unsigned short* lp = list + (size_t)tile * CAP + chunk * CHK;
        if (lane < n) {
            const int fidx = lp[lane];                 // coalesced 2B/lane
            const float4* p = fd + (size_t)fidx * 4;   // 3 dwordx4, batched vmcnt
            float4 b0 = p[0];
            float4 b1 = p[1];
            float4 b2 = p[2];
            sd[lane * 3 + 0] = b0;
            sd[lane * 3 + 1] = b1;
            sd[lane * 3 + 2] = b2;
        }
        // wave-internal write->read ordering (no block barrier: trip counts differ)
        asm volatile("s_waitcnt lgkmcnt(0)" ::: "memory");

        float mx[4] = {0.0f, 0.0f, 0.0f, 0.0f};

#pragma unroll 2
        for (int e = 0; e < n; ++e) {
            float4 a0 = sd[e * 3 + 0];   // uniform addr -> LDS broadcast
            float4 a1 = sd[e * 3 + 1];
            float4 a2 = sd[e * 3 + 2];
            float dx0 = a0.x - px, dx1 = a0.z - px, dx2 = a1.x - px;
#pragma unroll
            for (int r = 0; r < 4; ++r) {
                float dy0 = a0.y - py[r], dy1 = a0.w - py[r], dy2 = a1.y - py[r];
                float e0 = dx1 * dy2 - dx2 * dy1;
                float e1 = dx2 * dy0 - dx0 * dy2;
                float w0 = e0 * a1.z;
                float w1 = e1 * a1.z;
                float w2 = 1.0f - w0 - w1;
                float invz = w0 * a1.w + w1 * a2.x + w2 * a2.y;
                float invzc = fmaxf(invz, 1e-6f);
                // all(w>=0) <=> min3(w0,w1,w2)>=0 (exact; mult by positive ia
                // preserves sign). valid NEAR<zp<FAR <=> 0.01 < invzc < 10.
                float wmin = fminf(fminf(w0, w1), w2);
                bool ok = (wmin >= 0.0f) && (invzc < 10.0f) && (invzc > 0.01f);
                if (ok) mx[r] = fmaxf(mx[r], invzc);
            }
        }
#pragma unroll
        for (int r = 0; r < 4; ++r) {
            if (mx[r] > 0.0f) {
                float zp = 1.0f / mx[r];  // correctly-rounded 1/x monotone => min-exact
                unsigned int zbits = __float_as_uint(zp);
                if (zbits < zcur[r]) atomicMin(&zb[row[r] * IS + j], zbits);
            }
        }
    }
}

extern "C" void kernel_launch(void* const* d_in, const int* in_sizes, int n_in,
                              void* d_out, int out_size, void* d_ws, size_t ws_size,
                              hipStream_t stream) {
    const float* verts = (const float*)d_in[0];
    const int* faces = (const int*)d_in[1];
    unsigned int* zb = (unsigned int*)d_out;  // float bits, min'd in place

    const int nf = in_sizes[1] / 3;  // 5000 (< CAP and < 65536: ushort indices ok)

    char* ws = (char*)d_ws;
    size_t off = 0;
    float4* fd = (float4*)(ws + off);            off += (size_t)nf * 64;          // 320 KB
    off = (off + 255) & ~(size_t)255;
    int* count = (int*)(ws + off);               off += NTILES * 4;               // 1 KB
    off = (off + 255) & ~(size_t)255;
    int* misc = (int*)(ws + off);                off += 512;  // [0]=ticket, [64]=nitems
    int* items = (int*)(ws + off);               off += (size_t)MAXITEMS * 4;     // 160 KB
    off = (off + 255) & ~(size_t)255;
    unsigned short* list = (unsigned short*)(ws + off);  // 256*5120*2 = 2.62 MB

    const int nb = (nf + 255) / 256;  // 20 blocks

    kinit<<<(IS * IS) / 256, 256, 0, stream>>>(zb, count, misc);
    kbinprep<<<nb, 256, 0, stream>>>(verts, faces, fd, count, list, misc, items, nf);
    kraster<<<RBLOCKS, 256, 0, stream>>>(fd, list, items, misc, zb);
}